// Round 2
// baseline (849.827 us; speedup 1.0000x reference)
//
#include <hip/hip_runtime.h>
#include <hip/hip_bf16.h>
#include <math.h>

// BahdanauAttention: B=32, S=2048, H=1024, fp32 in/out.
//   q_proj = query@Wa^T + Wa_b + Ua_b   (fold both biases; Va_b dropped: softmax shift-invariant)
//   scores[b,s] = sum_o tanh(q_proj[b,o] + sum_h keys[b,s,h]*Ua_w[o,h]) * Va_w[o]
//   weights = softmax_s(scores); context = weights @ keys
// Big GEMM (M=65536,N=1024,K=1024) in bf16 MFMA 16x16x32, fused tanh/Va epilogue,
// per-row atomicAdd of score partials across 8 column-blocks.

#define B_ 32
#define S_ 2048
#define H_ 1024

typedef __bf16 bf16x8 __attribute__((ext_vector_type(8)));
typedef float floatx4 __attribute__((ext_vector_type(4)));

// fp32 -> bf16 round-to-nearest-even, returns the 16-bit pattern in the low half.
__device__ inline unsigned bf16_rne(float f) {
  unsigned u = __builtin_bit_cast(unsigned, f);
  return (u + 0x7fffu + ((u >> 16) & 1u)) >> 16;
}
// pack two fp32 into a bf16x2 dword (x in low 16 bits = first in memory).
__device__ inline unsigned pk2(float x, float y) {
  return bf16_rne(x) | (bf16_rne(y) << 16);
}

// ---------------- Kernel 1: q_proj (+ folded biases) ----------------
// grid 128 = 32 b * 4 o-splits, block 256.
__global__ __launch_bounds__(256) void qproj_kernel(
    const float* __restrict__ query, const float* __restrict__ Wa_w,
    const float* __restrict__ Wa_b, const float* __restrict__ Ua_b,
    float* __restrict__ qp) {
  const int b = blockIdx.x >> 2;
  const int os = blockIdx.x & 3;
  const int tid = threadIdx.x;
  const int lane = tid & 63;
  const int w = tid >> 6;
  __shared__ float qsh[H_];
  *(float4*)&qsh[tid * 4] = *(const float4*)(query + b * H_ + tid * 4);
  __syncthreads();
  for (int t = 0; t < 64; ++t) {
    const int o = os * 256 + w * 64 + t;
    const float* wr = Wa_w + (size_t)o * H_;
    float p = 0.f;
#pragma unroll
    for (int j = 0; j < 16; ++j) p += wr[lane + 64 * j] * qsh[lane + 64 * j];
#pragma unroll
    for (int m = 32; m; m >>= 1) p += __shfl_xor(p, m);
    if (lane == 0) qp[b * H_ + o] = p + Wa_b[o] + Ua_b[o];
  }
}

// ---------------- Kernel 2: fused GEMM + tanh + Va reduction -> scores ----------------
// grid 4096 = 512 row-blocks x 8 col-blocks (col fastest for keys L2/LLC reuse), block 256.
__global__ __launch_bounds__(256) void scores_kernel(
    const float* __restrict__ keys, const float* __restrict__ Ua_w,
    const float* __restrict__ qp, const float* __restrict__ Va_w,
    float* __restrict__ scores) {
  const int tid = threadIdx.x;
  const int rb = blockIdx.x >> 3;
  const int cb = blockIdx.x & 7;
  const int row0 = rb * 128;
  const int c0 = cb * 128;
  const int bq = row0 >> 11;          // batch index (2048 rows per b; 128 | 2048)
  const int lane = tid & 63;
  const int w = tid >> 6;
  const int wm = w >> 1, wn = w & 1;  // 2x2 waves -> 64x64 each
  const int q4 = lane >> 4, n16 = lane & 15;

  // stride 40 bf16 = 80B: fragment b128 reads land 2-way max on banks (free)
  __shared__ __align__(16) unsigned short Asm[128][40];
  __shared__ __align__(16) unsigned short Bsm[128][40];
  __shared__ float red[2][128];

  floatx4 acc[4][4];
#pragma unroll
  for (int i = 0; i < 4; ++i)
#pragma unroll
    for (int j = 0; j < 4; ++j) acc[i][j] = {0.f, 0.f, 0.f, 0.f};

  for (int kt = 0; kt < 32; ++kt) {
    const int k0 = kt * 32;
    __syncthreads();  // previous iter's fragment reads done
    // stage A (keys rows) and B (Ua_w rows), fp32 -> bf16, 128x32 each
#pragma unroll
    for (int rep = 0; rep < 4; ++rep) {
      const int idx4 = rep * 256 + tid;   // 1024 float4s per matrix
      const int r = idx4 >> 3;            // 0..127
      const int c4 = (idx4 & 7) << 2;     // 0..28
      const float4 va = *(const float4*)(keys + (size_t)(row0 + r) * H_ + k0 + c4);
      *(uint2*)&Asm[r][c4] = make_uint2(pk2(va.x, va.y), pk2(va.z, va.w));
      const float4 vb = *(const float4*)(Ua_w + (size_t)(c0 + r) * H_ + k0 + c4);
      *(uint2*)&Bsm[r][c4] = make_uint2(pk2(vb.x, vb.y), pk2(vb.z, vb.w));
    }
    __syncthreads();
    bf16x8 af[4], bfr[4];
#pragma unroll
    for (int i = 0; i < 4; ++i)
      af[i] = *(const bf16x8*)&Asm[wm * 64 + i * 16 + n16][q4 * 8];
#pragma unroll
    for (int j = 0; j < 4; ++j)
      bfr[j] = *(const bf16x8*)&Bsm[wn * 64 + j * 16 + n16][q4 * 8];
#pragma unroll
    for (int i = 0; i < 4; ++i)
#pragma unroll
      for (int j = 0; j < 4; ++j)
        acc[i][j] = __builtin_amdgcn_mfma_f32_16x16x32_bf16(af[i], bfr[j], acc[i][j], 0, 0, 0);
  }

  // epilogue: e = tanh(kp + qp[col]) * Va[col]; reduce over this block's 128 cols
  // acc[i][j][r] is (row = wm*64+i*16+q4*4+r, col = wn*64+j*16+n16)
  float rsum[4][4];
#pragma unroll
  for (int i = 0; i < 4; ++i)
#pragma unroll
    for (int r = 0; r < 4; ++r) rsum[i][r] = 0.f;
#pragma unroll
  for (int j = 0; j < 4; ++j) {
    const int col = c0 + wn * 64 + j * 16 + n16;
    const float qv = qp[bq * H_ + col];
    const float vv = Va_w[col];
#pragma unroll
    for (int i = 0; i < 4; ++i)
#pragma unroll
      for (int r = 0; r < 4; ++r)
        rsum[i][r] += tanhf(acc[i][j][r] + qv) * vv;
  }
  // reduce across the 16 lanes (n16) that share the same rows
#pragma unroll
  for (int i = 0; i < 4; ++i)
#pragma unroll
    for (int r = 0; r < 4; ++r) {
      float v = rsum[i][r];
      v += __shfl_xor(v, 1);
      v += __shfl_xor(v, 2);
      v += __shfl_xor(v, 4);
      v += __shfl_xor(v, 8);
      rsum[i][r] = v;
    }
  if (n16 == 0) {
#pragma unroll
    for (int i = 0; i < 4; ++i)
#pragma unroll
      for (int r = 0; r < 4; ++r)
        red[wn][wm * 64 + i * 16 + q4 * 4 + r] = rsum[i][r];
  }
  __syncthreads();
  if (tid < 128)
    atomicAdd(scores + row0 + tid, red[0][tid] + red[1][tid]);
}

// ---------------- Kernel 3: softmax over S, in place (scores -> weights) ----------------
__global__ __launch_bounds__(256) void softmax_kernel(float* __restrict__ sw) {
  const int b = blockIdx.x, tid = threadIdx.x;
  float v[8];
#pragma unroll
  for (int k = 0; k < 8; ++k) v[k] = sw[b * S_ + tid + 256 * k];
  float mx = v[0];
#pragma unroll
  for (int k = 1; k < 8; ++k) mx = fmaxf(mx, v[k]);
#pragma unroll
  for (int m = 32; m; m >>= 1) mx = fmaxf(mx, __shfl_xor(mx, m));
  __shared__ float sred[4], ssum[4];
  if ((tid & 63) == 0) sred[tid >> 6] = mx;
  __syncthreads();
  mx = fmaxf(fmaxf(sred[0], sred[1]), fmaxf(sred[2], sred[3]));
  float e[8], s = 0.f;
#pragma unroll
  for (int k = 0; k < 8; ++k) { e[k] = expf(v[k] - mx); s += e[k]; }
#pragma unroll
  for (int m = 32; m; m >>= 1) s += __shfl_xor(s, m);
  if ((tid & 63) == 0) ssum[tid >> 6] = s;
  __syncthreads();
  s = ssum[0] + ssum[1] + ssum[2] + ssum[3];
  const float inv = 1.0f / s;
#pragma unroll
  for (int k = 0; k < 8; ++k) sw[b * S_ + tid + 256 * k] = e[k] * inv;
}

// ---------------- Kernel 4: context = weights @ keys ----------------
// grid 256 = 32 b x 8 s-chunks of 256; atomicAdd partials into zeroed d_out.
__global__ __launch_bounds__(256) void context_kernel(
    const float* __restrict__ keys, const float* __restrict__ weights,
    float* __restrict__ ctx) {
  const int b = blockIdx.x >> 3;
  const int ch = blockIdx.x & 7;
  const int h4 = threadIdx.x * 4;
  const int s0 = ch * 256;
  float4 acc = {0.f, 0.f, 0.f, 0.f};
  for (int s = 0; s < 256; ++s) {
    const float wv = weights[b * S_ + s0 + s];
    const float4 kv = *(const float4*)(keys + (size_t)(b * S_ + s0 + s) * H_ + h4);
    acc.x += wv * kv.x; acc.y += wv * kv.y; acc.z += wv * kv.z; acc.w += wv * kv.w;
  }
  atomicAdd(ctx + b * H_ + h4 + 0, acc.x);
  atomicAdd(ctx + b * H_ + h4 + 1, acc.y);
  atomicAdd(ctx + b * H_ + h4 + 2, acc.z);
  atomicAdd(ctx + b * H_ + h4 + 3, acc.w);
}

extern "C" void kernel_launch(void* const* d_in, const int* in_sizes, int n_in,
                              void* d_out, int out_size, void* d_ws, size_t ws_size,
                              hipStream_t stream) {
  const float* query = (const float*)d_in[0];
  const float* keys  = (const float*)d_in[1];
  const float* Wa_w  = (const float*)d_in[2];
  const float* Wa_b  = (const float*)d_in[3];
  const float* Ua_w  = (const float*)d_in[4];
  const float* Ua_b  = (const float*)d_in[5];
  const float* Va_w  = (const float*)d_in[6];
  // d_in[7] = Va_b (softmax shift-invariant, unused), d_in[8] = idx (unused)

  float* out = (float*)d_out;
  float* ctx = out;            // (B,1,H) = 32768 floats
  float* sw  = out + B_ * H_;  // scores -> weights (B,1,S) = 65536 floats
  float* qp  = (float*)d_ws;   // 32*1024 floats = 128 KB scratch

  // zero context (atomic target) + scores (atomic target); weights overwritten later
  (void)hipMemsetAsync(d_out, 0, (size_t)out_size * sizeof(float), stream);

  qproj_kernel<<<128, 256, 0, stream>>>(query, Wa_w, Wa_b, Ua_b, qp);
  scores_kernel<<<4096, 256, 0, stream>>>(keys, Ua_w, qp, Va_w, sw);
  softmax_kernel<<<B_, 256, 0, stream>>>(sw);
  context_kernel<<<256, 256, 0, stream>>>(keys, sw, ctx);
}

// Round 3
// 748.942 us; speedup vs baseline: 1.1347x; 1.1347x over previous
//
#include <hip/hip_runtime.h>
#include <hip/hip_bf16.h>
#include <math.h>

// BahdanauAttention: B=32, S=2048, H=1024, fp32 in/out.
//   scores[b,s] = sum_o tanh( (query@Wa^T + Wa_b + Ua_b)[b,o] + (keys@Ua^T)[b,s,o] ) * Va_w[o]
//   weights = softmax_s(scores); context = weights @ keys.   (Va_b dropped: softmax shift-inv.)
// Round 3: pre-convert keys/Ua_w to bf16 in ws; scores GEMM uses global_load_lds width=16
// (m97 structure, no VALU staging); XCD-aware swizzle so the 8 col-blocks sharing a keys
// tile land on one XCD's L2; context kernel gets 4x more blocks.

#define B_ 32
#define S_ 2048
#define H_ 1024
#define M_ (B_ * S_)  // 65536 GEMM rows

typedef __bf16 bf16x8 __attribute__((ext_vector_type(8)));
typedef float floatx4 __attribute__((ext_vector_type(4)));

// fp32 -> bf16 round-to-nearest-even (bit pattern in low 16).
__device__ inline unsigned bf16_rne(float f) {
  unsigned u = __builtin_bit_cast(unsigned, f);
  return (u + 0x7fffu + ((u >> 16) & 1u)) >> 16;
}
__device__ inline unsigned pk2(float x, float y) {  // x = low 16 = first in memory
  return bf16_rne(x) | (bf16_rne(y) << 16);
}

// async global->LDS, 16B per lane; LDS dest = wave-uniform base + lane*16.
#define GLDS(g, l)                                                    \
  __builtin_amdgcn_global_load_lds(                                   \
      (const __attribute__((address_space(1))) void*)(g),             \
      (__attribute__((address_space(3))) void*)(l), 16, 0, 0)

// ---------------- fp32 -> bf16 bulk convert (8 floats -> one 16B store) ----------------
__global__ __launch_bounds__(256) void convert_kernel(
    const float* __restrict__ src, unsigned short* __restrict__ dst, int n8) {
  const int stride = gridDim.x * 256;
  for (int i = blockIdx.x * 256 + threadIdx.x; i < n8; i += stride) {
    const float4 a = ((const float4*)src)[(size_t)i * 2];
    const float4 b = ((const float4*)src)[(size_t)i * 2 + 1];
    uint4 o;
    o.x = pk2(a.x, a.y); o.y = pk2(a.z, a.w);
    o.z = pk2(b.x, b.y); o.w = pk2(b.z, b.w);
    ((uint4*)dst)[i] = o;
  }
}

// ---------------- q_proj (+ folded Wa_b + Ua_b) ----------------
__global__ __launch_bounds__(256) void qproj_kernel(
    const float* __restrict__ query, const float* __restrict__ Wa_w,
    const float* __restrict__ Wa_b, const float* __restrict__ Ua_b,
    float* __restrict__ qp) {
  const int b = blockIdx.x >> 2;
  const int os = blockIdx.x & 3;
  const int tid = threadIdx.x;
  const int lane = tid & 63;
  const int w = tid >> 6;
  __shared__ float qsh[H_];
  *(float4*)&qsh[tid * 4] = *(const float4*)(query + b * H_ + tid * 4);
  __syncthreads();
  for (int t = 0; t < 64; ++t) {
    const int o = os * 256 + w * 64 + t;
    const float* wr = Wa_w + (size_t)o * H_;
    float p = 0.f;
#pragma unroll
    for (int j = 0; j < 16; ++j) p += wr[lane + 64 * j] * qsh[lane + 64 * j];
#pragma unroll
    for (int m = 32; m; m >>= 1) p += __shfl_xor(p, m);
    if (lane == 0) qp[b * H_ + o] = p + Wa_b[o] + Ua_b[o];
  }
}

// XCD swizzle: blockIdx round-robins across 8 XCDs (idx%8). Make the 8 col-blocks of one
// row-block share idx mod 8 so they run on ONE XCD and share its L2 keys tile.
__device__ inline void swizzle_rc(int idx, int& rb, int& cb) {
  cb = (idx >> 3) & 7;
  rb = (idx & 7) | ((idx >> 6) << 3);
}

// ---------------- scores: bf16 GEMM (M=65536,N=1024,K=1024) + tanh/Va epilogue ----------------
// m97 structure: 128x128 tile, BK=32, global_load_lds staging, 2x2 waves of 4x4 16x16x32 MFMA.
__global__ __launch_bounds__(256) void scores_bf16_kernel(
    const unsigned short* __restrict__ kbf, const unsigned short* __restrict__ ubf,
    const float* __restrict__ qp, const float* __restrict__ Va_w,
    float* __restrict__ scores) {
  const int tid = threadIdx.x;
  int rb, cb;
  swizzle_rc(blockIdx.x, rb, cb);
  const int row0 = rb * 128, c0 = cb * 128;
  const int bq = row0 >> 11;
  const int lane = tid & 63;
  const int w = tid >> 6;
  const int wm = w >> 1, wn = w & 1;
  const int q4 = lane >> 4, n16 = lane & 15;

  // unpadded: global_load_lds needs LDS contiguous in lane order (lane*16B).
  __shared__ __align__(16) unsigned short Asm[128][32];
  __shared__ __align__(16) unsigned short Bsm[128][32];
  __shared__ float red[2][128];

  floatx4 acc[4][4];
#pragma unroll
  for (int i = 0; i < 4; ++i)
#pragma unroll
    for (int j = 0; j < 4; ++j) acc[i][j] = {0.f, 0.f, 0.f, 0.f};

  // wave w stages rows [w*32, w*32+32) of A and B: 2 instrs x 16 rows (1KB each).
  // lane l -> row l>>2, byte (l&3)*16 within chunk.
  const int r0a = w * 32;
  const int lr = lane >> 2;
  const int lc = (lane & 3) * 8;  // elements
  const unsigned short* gA0 = kbf + (size_t)(row0 + r0a + lr) * H_ + lc;
  const unsigned short* gA1 = kbf + (size_t)(row0 + r0a + 16 + lr) * H_ + lc;
  const unsigned short* gB0 = ubf + (size_t)(c0 + r0a + lr) * H_ + lc;
  const unsigned short* gB1 = ubf + (size_t)(c0 + r0a + 16 + lr) * H_ + lc;
  unsigned short* lA0 = &Asm[r0a][0];
  unsigned short* lA1 = &Asm[r0a + 16][0];
  unsigned short* lB0 = &Bsm[r0a][0];
  unsigned short* lB1 = &Bsm[r0a + 16][0];

  for (int kt = 0; kt < 32; ++kt) {
    const int k0 = kt * 32;
    __syncthreads();  // previous iter's fragment reads done before overwrite
    GLDS(gA0 + k0, lA0);
    GLDS(gA1 + k0, lA1);
    GLDS(gB0 + k0, lB0);
    GLDS(gB1 + k0, lB1);
    __syncthreads();  // drains vmcnt (global_load_lds) per barrier semantics
    bf16x8 af[4], bfr[4];
#pragma unroll
    for (int i = 0; i < 4; ++i)
      af[i] = *(const bf16x8*)&Asm[wm * 64 + i * 16 + n16][q4 * 8];
#pragma unroll
    for (int j = 0; j < 4; ++j)
      bfr[j] = *(const bf16x8*)&Bsm[wn * 64 + j * 16 + n16][q4 * 8];
#pragma unroll
    for (int i = 0; i < 4; ++i)
#pragma unroll
      for (int j = 0; j < 4; ++j)
        acc[i][j] = __builtin_amdgcn_mfma_f32_16x16x32_bf16(af[i], bfr[j], acc[i][j], 0, 0, 0);
  }

  // epilogue: sum_j tanh(acc + qp[col]) * Va[col] over this block's 128 cols.
  // acc[i][j][r] = (row = wm*64+i*16+q4*4+r, col = wn*64+j*16+n16)
  float rsum[4][4];
#pragma unroll
  for (int i = 0; i < 4; ++i)
#pragma unroll
    for (int r = 0; r < 4; ++r) rsum[i][r] = 0.f;
#pragma unroll
  for (int j = 0; j < 4; ++j) {
    const int col = c0 + wn * 64 + j * 16 + n16;
    const float qv = qp[bq * H_ + col];
    const float vv = Va_w[col];
#pragma unroll
    for (int i = 0; i < 4; ++i)
#pragma unroll
      for (int r = 0; r < 4; ++r)
        rsum[i][r] += tanhf(acc[i][j][r] + qv) * vv;
  }
#pragma unroll
  for (int i = 0; i < 4; ++i)
#pragma unroll
    for (int r = 0; r < 4; ++r) {
      float v = rsum[i][r];
      v += __shfl_xor(v, 1);
      v += __shfl_xor(v, 2);
      v += __shfl_xor(v, 4);
      v += __shfl_xor(v, 8);
      rsum[i][r] = v;
    }
  if (n16 == 0) {
#pragma unroll
    for (int i = 0; i < 4; ++i)
#pragma unroll
      for (int r = 0; r < 4; ++r)
        red[wn][wm * 64 + i * 16 + q4 * 4 + r] = rsum[i][r];
  }
  __syncthreads();
  if (tid < 128) atomicAdd(scores + row0 + tid, red[0][tid] + red[1][tid]);
}

// ---------------- fallback scores (fp32 sources, in-kernel convert) for small ws ----------------
__global__ __launch_bounds__(256) void scores_f32_kernel(
    const float* __restrict__ keys, const float* __restrict__ Ua_w,
    const float* __restrict__ qp, const float* __restrict__ Va_w,
    float* __restrict__ scores) {
  const int tid = threadIdx.x;
  int rb, cb;
  swizzle_rc(blockIdx.x, rb, cb);
  const int row0 = rb * 128, c0 = cb * 128;
  const int bq = row0 >> 11;
  const int lane = tid & 63;
  const int w = tid >> 6;
  const int wm = w >> 1, wn = w & 1;
  const int q4 = lane >> 4, n16 = lane & 15;

  __shared__ __align__(16) unsigned short Asm[128][40];
  __shared__ __align__(16) unsigned short Bsm[128][40];
  __shared__ float red[2][128];

  floatx4 acc[4][4];
#pragma unroll
  for (int i = 0; i < 4; ++i)
#pragma unroll
    for (int j = 0; j < 4; ++j) acc[i][j] = {0.f, 0.f, 0.f, 0.f};

  for (int kt = 0; kt < 32; ++kt) {
    const int k0 = kt * 32;
    __syncthreads();
#pragma unroll
    for (int rep = 0; rep < 4; ++rep) {
      const int idx4 = rep * 256 + tid;
      const int r = idx4 >> 3;
      const int c4 = (idx4 & 7) << 2;
      const float4 va = *(const float4*)(keys + (size_t)(row0 + r) * H_ + k0 + c4);
      *(uint2*)&Asm[r][c4] = make_uint2(pk2(va.x, va.y), pk2(va.z, va.w));
      const float4 vb = *(const float4*)(Ua_w + (size_t)(c0 + r) * H_ + k0 + c4);
      *(uint2*)&Bsm[r][c4] = make_uint2(pk2(vb.x, vb.y), pk2(vb.z, vb.w));
    }
    __syncthreads();
    bf16x8 af[4], bfr[4];
#pragma unroll
    for (int i = 0; i < 4; ++i)
      af[i] = *(const bf16x8*)&Asm[wm * 64 + i * 16 + n16][q4 * 8];
#pragma unroll
    for (int j = 0; j < 4; ++j)
      bfr[j] = *(const bf16x8*)&Bsm[wn * 64 + j * 16 + n16][q4 * 8];
#pragma unroll
    for (int i = 0; i < 4; ++i)
#pragma unroll
      for (int j = 0; j < 4; ++j)
        acc[i][j] = __builtin_amdgcn_mfma_f32_16x16x32_bf16(af[i], bfr[j], acc[i][j], 0, 0, 0);
  }

  float rsum[4][4];
#pragma unroll
  for (int i = 0; i < 4; ++i)
#pragma unroll
    for (int r = 0; r < 4; ++r) rsum[i][r] = 0.f;
#pragma unroll
  for (int j = 0; j < 4; ++j) {
    const int col = c0 + wn * 64 + j * 16 + n16;
    const float qv = qp[bq * H_ + col];
    const float vv = Va_w[col];
#pragma unroll
    for (int i = 0; i < 4; ++i)
#pragma unroll
      for (int r = 0; r < 4; ++r)
        rsum[i][r] += tanhf(acc[i][j][r] + qv) * vv;
  }
#pragma unroll
  for (int i = 0; i < 4; ++i)
#pragma unroll
    for (int r = 0; r < 4; ++r) {
      float v = rsum[i][r];
      v += __shfl_xor(v, 1);
      v += __shfl_xor(v, 2);
      v += __shfl_xor(v, 4);
      v += __shfl_xor(v, 8);
      rsum[i][r] = v;
    }
  if (n16 == 0) {
#pragma unroll
    for (int i = 0; i < 4; ++i)
#pragma unroll
      for (int r = 0; r < 4; ++r)
        red[wn][wm * 64 + i * 16 + q4 * 4 + r] = rsum[i][r];
  }
  __syncthreads();
  if (tid < 128) atomicAdd(scores + row0 + tid, red[0][tid] + red[1][tid]);
}

// ---------------- softmax over S, in place ----------------
__global__ __launch_bounds__(256) void softmax_kernel(float* __restrict__ sw) {
  const int b = blockIdx.x, tid = threadIdx.x;
  float v[8];
#pragma unroll
  for (int k = 0; k < 8; ++k) v[k] = sw[b * S_ + tid + 256 * k];
  float mx = v[0];
#pragma unroll
  for (int k = 1; k < 8; ++k) mx = fmaxf(mx, v[k]);
#pragma unroll
  for (int m = 32; m; m >>= 1) mx = fmaxf(mx, __shfl_xor(mx, m));
  __shared__ float sred[4], ssum[4];
  if ((tid & 63) == 0) sred[tid >> 6] = mx;
  __syncthreads();
  mx = fmaxf(fmaxf(sred[0], sred[1]), fmaxf(sred[2], sred[3]));
  float e[8], s = 0.f;
#pragma unroll
  for (int k = 0; k < 8; ++k) { e[k] = expf(v[k] - mx); s += e[k]; }
#pragma unroll
  for (int m = 32; m; m >>= 1) s += __shfl_xor(s, m);
  if ((tid & 63) == 0) ssum[tid >> 6] = s;
  __syncthreads();
  s = ssum[0] + ssum[1] + ssum[2] + ssum[3];
  const float inv = 1.0f / s;
#pragma unroll
  for (int k = 0; k < 8; ++k) sw[b * S_ + tid + 256 * k] = e[k] * inv;
}

// ---------------- context = weights @ keys (fp32 keys for precision) ----------------
// grid 1024 = 32 b x 32 s-chunks of 64; 4 blocks/CU for latency hiding.
__global__ __launch_bounds__(256) void context_kernel(
    const float* __restrict__ keys, const float* __restrict__ weights,
    float* __restrict__ ctx) {
  const int b = blockIdx.x >> 5;
  const int ch = blockIdx.x & 31;
  const int h4 = threadIdx.x * 4;
  const int s0 = ch * 64;
  const float* kp = keys + (size_t)(b * S_ + s0) * H_ + h4;
  const float* wp = weights + b * S_ + s0;
  float4 acc = {0.f, 0.f, 0.f, 0.f};
#pragma unroll 4
  for (int s = 0; s < 64; ++s) {
    const float wv = wp[s];
    const float4 kv = *(const float4*)(kp + (size_t)s * H_);
    acc.x += wv * kv.x; acc.y += wv * kv.y; acc.z += wv * kv.z; acc.w += wv * kv.w;
  }
  atomicAdd(ctx + b * H_ + h4 + 0, acc.x);
  atomicAdd(ctx + b * H_ + h4 + 1, acc.y);
  atomicAdd(ctx + b * H_ + h4 + 2, acc.z);
  atomicAdd(ctx + b * H_ + h4 + 3, acc.w);
}

extern "C" void kernel_launch(void* const* d_in, const int* in_sizes, int n_in,
                              void* d_out, int out_size, void* d_ws, size_t ws_size,
                              hipStream_t stream) {
  const float* query = (const float*)d_in[0];
  const float* keys  = (const float*)d_in[1];
  const float* Wa_w  = (const float*)d_in[2];
  const float* Wa_b  = (const float*)d_in[3];
  const float* Ua_w  = (const float*)d_in[4];
  const float* Ua_b  = (const float*)d_in[5];
  const float* Va_w  = (const float*)d_in[6];
  // d_in[7] = Va_b (softmax shift-invariant), d_in[8] = idx — unused.

  float* out = (float*)d_out;
  float* ctx = out;            // (B,1,H)
  float* sw  = out + B_ * H_;  // scores -> weights (B,1,S)

  const size_t kb  = (size_t)M_ * H_ * 2;  // 128 MiB bf16 keys
  const size_t ub  = (size_t)H_ * H_ * 2;  // 2 MiB bf16 Ua_w
  const size_t qpb = (size_t)B_ * H_ * 4;  // 128 KiB q_proj
  const bool fast = ws_size >= kb + ub + qpb;

  (void)hipMemsetAsync(d_out, 0, (size_t)out_size * sizeof(float), stream);

  if (fast) {
    unsigned short* kbf = (unsigned short*)d_ws;
    unsigned short* ubf = (unsigned short*)((char*)d_ws + kb);
    float* qp = (float*)((char*)d_ws + kb + ub);
    convert_kernel<<<2048, 256, 0, stream>>>(keys, kbf, M_ * H_ / 8);
    convert_kernel<<<256, 256, 0, stream>>>(Ua_w, ubf, H_ * H_ / 8);
    qproj_kernel<<<128, 256, 0, stream>>>(query, Wa_w, Wa_b, Ua_b, qp);
    scores_bf16_kernel<<<4096, 256, 0, stream>>>(kbf, ubf, qp, Va_w, sw);
  } else {
    float* qp = (float*)d_ws;
    qproj_kernel<<<128, 256, 0, stream>>>(query, Wa_w, Wa_b, Ua_b, qp);
    scores_f32_kernel<<<4096, 256, 0, stream>>>(keys, Ua_w, qp, Va_w, sw);
  }
  softmax_kernel<<<B_, 256, 0, stream>>>(sw);
  context_kernel<<<1024, 256, 0, stream>>>(keys, sw, ctx);
}

// Round 4
// 664.735 us; speedup vs baseline: 1.2784x; 1.1267x over previous
//
#include <hip/hip_runtime.h>
#include <hip/hip_bf16.h>
#include <math.h>

// BahdanauAttention: B=32, S=2048, H=1024, fp32 in/out.
// R4: fast tanh (exp+rcp, ~7 ops vs libm ~35 — epilogue was ~124us of scores);
//     XOR-swizzled LDS chunks (kills 8-way ds_read_b128 bank conflicts, legal with
//     global_load_lds because we permute the per-lane GLOBAL source, not the LDS dest);
//     atomic-free 2-stage context; qproj reads Wa_w once (thread per (b,o)).

#define B_ 32
#define S_ 2048
#define H_ 1024
#define M_ (B_ * S_)

typedef __bf16 bf16x8 __attribute__((ext_vector_type(8)));
typedef float floatx4 __attribute__((ext_vector_type(4)));

__device__ inline unsigned bf16_rne(float f) {
  unsigned u = __builtin_bit_cast(unsigned, f);
  return (u + 0x7fffu + ((u >> 16) & 1u)) >> 16;
}
__device__ inline unsigned pk2(float x, float y) {
  return bf16_rne(x) | (bf16_rne(y) << 16);
}

// tanh via v_exp_f32 + v_rcp_f32: rel err ~1e-6 (negligible vs bf16 GEMM 5e-4).
// clamp to +-8 (tanh(8)=1-4.5e-7) avoids exp overflow; 2 ops.
__device__ inline float fast_tanh(float x) {
  const float xc = fminf(fmaxf(x, -8.f), 8.f);
  const float e = __expf(2.f * xc);
  return (e - 1.f) * __builtin_amdgcn_rcpf(e + 1.f);
}

#define GLDS(g, l)                                                    \
  __builtin_amdgcn_global_load_lds(                                   \
      (const __attribute__((address_space(1))) void*)(g),             \
      (__attribute__((address_space(3))) void*)(l), 16, 0, 0)

// ---------------- fp32 -> bf16 bulk convert ----------------
__global__ __launch_bounds__(256) void convert_kernel(
    const float* __restrict__ src, unsigned short* __restrict__ dst, int n8) {
  const int stride = gridDim.x * 256;
  for (int i = blockIdx.x * 256 + threadIdx.x; i < n8; i += stride) {
    const float4 a = ((const float4*)src)[(size_t)i * 2];
    const float4 b = ((const float4*)src)[(size_t)i * 2 + 1];
    uint4 o;
    o.x = pk2(a.x, a.y); o.y = pk2(a.z, a.w);
    o.z = pk2(b.x, b.y); o.w = pk2(b.z, b.w);
    ((uint4*)dst)[i] = o;
  }
}

// ---------------- q_proj: thread per (b,o); Wa_w read once (broadcast across b-lanes) ----
__global__ __launch_bounds__(256) void qproj_kernel(
    const float* __restrict__ query, const float* __restrict__ Wa_w,
    const float* __restrict__ Wa_b, const float* __restrict__ Ua_b,
    float* __restrict__ qp) {
  const int g = blockIdx.x * 256 + threadIdx.x;  // 32768 threads
  const int b = g & 31;                          // lane-minor: Wa row broadcast in-wave
  const int o = g >> 5;
  const float4* wr = (const float4*)(Wa_w + (size_t)o * H_);
  const float4* qr = (const float4*)(query + (size_t)b * H_);
  float4 s4 = {0.f, 0.f, 0.f, 0.f};
#pragma unroll 8
  for (int k = 0; k < 256; ++k) {
    const float4 w = wr[k], q = qr[k];
    s4.x += w.x * q.x; s4.y += w.y * q.y; s4.z += w.z * q.z; s4.w += w.w * q.w;
  }
  qp[b * H_ + o] = (s4.x + s4.y) + (s4.z + s4.w) + Wa_b[o] + Ua_b[o];
}

// XCD swizzle: the 8 col-blocks of a row-block share idx%8 -> same XCD L2 keys tile.
__device__ inline void swizzle_rc(int idx, int& rb, int& cb) {
  cb = (idx >> 3) & 7;
  rb = (idx & 7) | ((idx >> 6) << 3);
}

// chunk permutation: f(r) over r mod 16; slot s of row r holds logical 16B-chunk s^f(r).
// Gives exactly 2 rows per bank-group on fragment reads (2-way = free, m136).
__device__ inline int chunk_f(int r) { return (r & 3) ^ ((r >> 2) & 3); }

// ---------------- scores: bf16 GEMM (65536x1024x1024) + tanh/Va epilogue ----------------
__global__ __launch_bounds__(256) void scores_bf16_kernel(
    const unsigned short* __restrict__ kbf, const unsigned short* __restrict__ ubf,
    const float* __restrict__ qp, const float* __restrict__ Va_w,
    float* __restrict__ scores) {
  const int tid = threadIdx.x;
  int rb, cb;
  swizzle_rc(blockIdx.x, rb, cb);
  const int row0 = rb * 128, c0 = cb * 128;
  const int bq = row0 >> 11;
  const int lane = tid & 63;
  const int w = tid >> 6;
  const int wm = w >> 1, wn = w & 1;
  const int q4 = lane >> 4, n16 = lane & 15;

  __shared__ __align__(16) unsigned short Asm[128][32];
  __shared__ __align__(16) unsigned short Bsm[128][32];
  __shared__ float red[2][128];

  floatx4 acc[4][4];
#pragma unroll
  for (int i = 0; i < 4; ++i)
#pragma unroll
    for (int j = 0; j < 4; ++j) acc[i][j] = {0.f, 0.f, 0.f, 0.f};

  // staging: wave w covers rows [w*32, w*32+32). lane l -> row l>>2, LDS slot l&3;
  // global chunk = slot ^ f(row)  (XOR bank-deswizzle on the SOURCE side).
  const int r0a = w * 32;
  const int lr = lane >> 2;
  const int lc = ((lane & 3) ^ chunk_f(lr)) * 8;  // elements
  const unsigned short* gA0 = kbf + (size_t)(row0 + r0a + lr) * H_ + lc;
  const unsigned short* gA1 = kbf + (size_t)(row0 + r0a + 16 + lr) * H_ + lc;
  const unsigned short* gB0 = ubf + (size_t)(c0 + r0a + lr) * H_ + lc;
  const unsigned short* gB1 = ubf + (size_t)(c0 + r0a + 16 + lr) * H_ + lc;
  unsigned short* lA0 = &Asm[r0a][0];
  unsigned short* lA1 = &Asm[r0a + 16][0];
  unsigned short* lB0 = &Bsm[r0a][0];
  unsigned short* lB1 = &Bsm[r0a + 16][0];

  const int fn = chunk_f(n16);  // fragment-read chunk permute

  for (int kt = 0; kt < 32; ++kt) {
    const int k0 = kt * 32;
    __syncthreads();
    GLDS(gA0 + k0, lA0);
    GLDS(gA1 + k0, lA1);
    GLDS(gB0 + k0, lB0);
    GLDS(gB1 + k0, lB1);
    __syncthreads();
    bf16x8 af[4], bfr[4];
#pragma unroll
    for (int i = 0; i < 4; ++i)
      af[i] = *(const bf16x8*)&Asm[wm * 64 + i * 16 + n16][(q4 ^ fn) * 8];
#pragma unroll
    for (int j = 0; j < 4; ++j)
      bfr[j] = *(const bf16x8*)&Bsm[wn * 64 + j * 16 + n16][(q4 ^ fn) * 8];
#pragma unroll
    for (int i = 0; i < 4; ++i)
#pragma unroll
      for (int j = 0; j < 4; ++j)
        acc[i][j] = __builtin_amdgcn_mfma_f32_16x16x32_bf16(af[i], bfr[j], acc[i][j], 0, 0, 0);
  }

  // epilogue: sum_cols tanh(kp + qp[col]) * Va[col]
  float rsum[4][4];
#pragma unroll
  for (int i = 0; i < 4; ++i)
#pragma unroll
    for (int r = 0; r < 4; ++r) rsum[i][r] = 0.f;
#pragma unroll
  for (int j = 0; j < 4; ++j) {
    const int col = c0 + wn * 64 + j * 16 + n16;
    const float qv = qp[bq * H_ + col];
    const float vv = Va_w[col];
#pragma unroll
    for (int i = 0; i < 4; ++i)
#pragma unroll
      for (int r = 0; r < 4; ++r)
        rsum[i][r] += fast_tanh(acc[i][j][r] + qv) * vv;
  }
#pragma unroll
  for (int i = 0; i < 4; ++i)
#pragma unroll
    for (int r = 0; r < 4; ++r) {
      float v = rsum[i][r];
      v += __shfl_xor(v, 1);
      v += __shfl_xor(v, 2);
      v += __shfl_xor(v, 4);
      v += __shfl_xor(v, 8);
      rsum[i][r] = v;
    }
  if (n16 == 0) {
#pragma unroll
    for (int i = 0; i < 4; ++i)
#pragma unroll
      for (int r = 0; r < 4; ++r)
        red[wn][wm * 64 + i * 16 + q4 * 4 + r] = rsum[i][r];
  }
  __syncthreads();
  if (tid < 128) atomicAdd(scores + row0 + tid, red[0][tid] + red[1][tid]);
}

// ---------------- fallback scores (fp32 sources, in-kernel convert) ----------------
__global__ __launch_bounds__(256) void scores_f32_kernel(
    const float* __restrict__ keys, const float* __restrict__ Ua_w,
    const float* __restrict__ qp, const float* __restrict__ Va_w,
    float* __restrict__ scores) {
  const int tid = threadIdx.x;
  int rb, cb;
  swizzle_rc(blockIdx.x, rb, cb);
  const int row0 = rb * 128, c0 = cb * 128;
  const int bq = row0 >> 11;
  const int lane = tid & 63;
  const int w = tid >> 6;
  const int wm = w >> 1, wn = w & 1;
  const int q4 = lane >> 4, n16 = lane & 15;

  __shared__ __align__(16) unsigned short Asm[128][40];
  __shared__ __align__(16) unsigned short Bsm[128][40];
  __shared__ float red[2][128];

  floatx4 acc[4][4];
#pragma unroll
  for (int i = 0; i < 4; ++i)
#pragma unroll
    for (int j = 0; j < 4; ++j) acc[i][j] = {0.f, 0.f, 0.f, 0.f};

  for (int kt = 0; kt < 32; ++kt) {
    const int k0 = kt * 32;
    __syncthreads();
#pragma unroll
    for (int rep = 0; rep < 4; ++rep) {
      const int idx4 = rep * 256 + tid;
      const int r = idx4 >> 3;
      const int c4 = (idx4 & 7) << 2;
      const float4 va = *(const float4*)(keys + (size_t)(row0 + r) * H_ + k0 + c4);
      *(uint2*)&Asm[r][c4] = make_uint2(pk2(va.x, va.y), pk2(va.z, va.w));
      const float4 vb = *(const float4*)(Ua_w + (size_t)(c0 + r) * H_ + k0 + c4);
      *(uint2*)&Bsm[r][c4] = make_uint2(pk2(vb.x, vb.y), pk2(vb.z, vb.w));
    }
    __syncthreads();
    bf16x8 af[4], bfr[4];
#pragma unroll
    for (int i = 0; i < 4; ++i)
      af[i] = *(const bf16x8*)&Asm[wm * 64 + i * 16 + n16][q4 * 8];
#pragma unroll
    for (int j = 0; j < 4; ++j)
      bfr[j] = *(const bf16x8*)&Bsm[wn * 64 + j * 16 + n16][q4 * 8];
#pragma unroll
    for (int i = 0; i < 4; ++i)
#pragma unroll
      for (int j = 0; j < 4; ++j)
        acc[i][j] = __builtin_amdgcn_mfma_f32_16x16x32_bf16(af[i], bfr[j], acc[i][j], 0, 0, 0);
  }

  float rsum[4][4];
#pragma unroll
  for (int i = 0; i < 4; ++i)
#pragma unroll
    for (int r = 0; r < 4; ++r) rsum[i][r] = 0.f;
#pragma unroll
  for (int j = 0; j < 4; ++j) {
    const int col = c0 + wn * 64 + j * 16 + n16;
    const float qv = qp[bq * H_ + col];
    const float vv = Va_w[col];
#pragma unroll
    for (int i = 0; i < 4; ++i)
#pragma unroll
      for (int r = 0; r < 4; ++r)
        rsum[i][r] += fast_tanh(acc[i][j][r] + qv) * vv;
  }
#pragma unroll
  for (int i = 0; i < 4; ++i)
#pragma unroll
    for (int r = 0; r < 4; ++r) {
      float v = rsum[i][r];
      v += __shfl_xor(v, 1);
      v += __shfl_xor(v, 2);
      v += __shfl_xor(v, 4);
      v += __shfl_xor(v, 8);
      rsum[i][r] = v;
    }
  if (n16 == 0) {
#pragma unroll
    for (int i = 0; i < 4; ++i)
#pragma unroll
      for (int r = 0; r < 4; ++r)
        red[wn][wm * 64 + i * 16 + q4 * 4 + r] = rsum[i][r];
  }
  __syncthreads();
  if (tid < 128) atomicAdd(scores + row0 + tid, red[0][tid] + red[1][tid]);
}

// ---------------- softmax over S, in place ----------------
__global__ __launch_bounds__(256) void softmax_kernel(float* __restrict__ sw) {
  const int b = blockIdx.x, tid = threadIdx.x;
  float v[8];
#pragma unroll
  for (int k = 0; k < 8; ++k) v[k] = sw[b * S_ + tid + 256 * k];
  float mx = v[0];
#pragma unroll
  for (int k = 1; k < 8; ++k) mx = fmaxf(mx, v[k]);
#pragma unroll
  for (int m = 32; m; m >>= 1) mx = fmaxf(mx, __shfl_xor(mx, m));
  __shared__ float sred[4], ssum[4];
  if ((tid & 63) == 0) sred[tid >> 6] = mx;
  __syncthreads();
  mx = fmaxf(fmaxf(sred[0], sred[1]), fmaxf(sred[2], sred[3]));
  float e[8], s = 0.f;
#pragma unroll
  for (int k = 0; k < 8; ++k) { e[k] = expf(v[k] - mx); s += e[k]; }
#pragma unroll
  for (int m = 32; m; m >>= 1) s += __shfl_xor(s, m);
  if ((tid & 63) == 0) ssum[tid >> 6] = s;
  __syncthreads();
  s = ssum[0] + ssum[1] + ssum[2] + ssum[3];
  const float inv = 1.0f / s;
#pragma unroll
  for (int k = 0; k < 8; ++k) sw[b * S_ + tid + 256 * k] = e[k] * inv;
}

// ---------------- context stage 1: per-(b,chunk) partials -> ws (no atomics) ----------------
__global__ __launch_bounds__(256) void context1_kernel(
    const float* __restrict__ keys, const float* __restrict__ weights,
    float* __restrict__ pctx) {
  const int b = blockIdx.x >> 5;
  const int ch = blockIdx.x & 31;
  const int h4 = threadIdx.x * 4;
  const int s0 = ch * 64;
  const float* kp = keys + (size_t)(b * S_ + s0) * H_ + h4;
  const float* wp = weights + b * S_ + s0;
  float4 acc = {0.f, 0.f, 0.f, 0.f};
#pragma unroll 4
  for (int s = 0; s < 64; ++s) {
    const float wv = wp[s];
    const float4 kv = *(const float4*)(kp + (size_t)s * H_);
    acc.x += wv * kv.x; acc.y += wv * kv.y; acc.z += wv * kv.z; acc.w += wv * kv.w;
  }
  *(float4*)(pctx + ((size_t)(b * 32 + ch)) * H_ + h4) = acc;
}

// ---------------- context stage 2: reduce 32 partials ----------------
__global__ __launch_bounds__(256) void context2_kernel(
    const float* __restrict__ pctx, float* __restrict__ ctx) {
  const int b = blockIdx.x;
  const int h4 = threadIdx.x * 4;
  float4 acc = {0.f, 0.f, 0.f, 0.f};
#pragma unroll 8
  for (int c = 0; c < 32; ++c) {
    const float4 v = *(const float4*)(pctx + ((size_t)(b * 32 + c)) * H_ + h4);
    acc.x += v.x; acc.y += v.y; acc.z += v.z; acc.w += v.w;
  }
  *(float4*)(ctx + b * H_ + h4) = acc;
}

// ---------------- fallback atomic context ----------------
__global__ __launch_bounds__(256) void context_atomic_kernel(
    const float* __restrict__ keys, const float* __restrict__ weights,
    float* __restrict__ ctx) {
  const int b = blockIdx.x >> 5;
  const int ch = blockIdx.x & 31;
  const int h4 = threadIdx.x * 4;
  const int s0 = ch * 64;
  const float* kp = keys + (size_t)(b * S_ + s0) * H_ + h4;
  const float* wp = weights + b * S_ + s0;
  float4 acc = {0.f, 0.f, 0.f, 0.f};
#pragma unroll 4
  for (int s = 0; s < 64; ++s) {
    const float wv = wp[s];
    const float4 kv = *(const float4*)(kp + (size_t)s * H_);
    acc.x += wv * kv.x; acc.y += wv * kv.y; acc.z += wv * kv.z; acc.w += wv * kv.w;
  }
  atomicAdd(ctx + b * H_ + h4 + 0, acc.x);
  atomicAdd(ctx + b * H_ + h4 + 1, acc.y);
  atomicAdd(ctx + b * H_ + h4 + 2, acc.z);
  atomicAdd(ctx + b * H_ + h4 + 3, acc.w);
}

extern "C" void kernel_launch(void* const* d_in, const int* in_sizes, int n_in,
                              void* d_out, int out_size, void* d_ws, size_t ws_size,
                              hipStream_t stream) {
  const float* query = (const float*)d_in[0];
  const float* keys  = (const float*)d_in[1];
  const float* Wa_w  = (const float*)d_in[2];
  const float* Wa_b  = (const float*)d_in[3];
  const float* Ua_w  = (const float*)d_in[4];
  const float* Ua_b  = (const float*)d_in[5];
  const float* Va_w  = (const float*)d_in[6];
  // d_in[7] = Va_b (softmax shift-invariant), d_in[8] = idx — unused.

  float* out = (float*)d_out;
  float* ctx = out;
  float* sw  = out + B_ * H_;

  // ws layout: qp (128K) | pctx (4M) | kbf (128M) | ubf (2M)
  const size_t qpb  = (size_t)B_ * H_ * 4;
  const size_t pcb  = (size_t)B_ * 32 * H_ * 4;
  const size_t kb   = (size_t)M_ * H_ * 2;
  const size_t ub   = (size_t)H_ * H_ * 2;
  float* qp = (float*)d_ws;
  float* pctx = (float*)((char*)d_ws + qpb);
  unsigned short* kbf = (unsigned short*)((char*)d_ws + qpb + pcb);
  unsigned short* ubf = (unsigned short*)((char*)d_ws + qpb + pcb + kb);
  const bool fast = ws_size >= qpb + pcb + kb + ub;
  const bool twostage = ws_size >= qpb + pcb;

  (void)hipMemsetAsync(d_out, 0, (size_t)out_size * sizeof(float), stream);

  qproj_kernel<<<128, 256, 0, stream>>>(query, Wa_w, Wa_b, Ua_b, qp);
  if (fast) {
    convert_kernel<<<2048, 256, 0, stream>>>(keys, kbf, M_ * H_ / 8);
    convert_kernel<<<256, 256, 0, stream>>>(Ua_w, ubf, H_ * H_ / 8);
    scores_bf16_kernel<<<4096, 256, 0, stream>>>(kbf, ubf, qp, Va_w, sw);
  } else {
    scores_f32_kernel<<<4096, 256, 0, stream>>>(keys, Ua_w, qp, Va_w, sw);
  }
  softmax_kernel<<<B_, 256, 0, stream>>>(sw);
  if (twostage) {
    context1_kernel<<<1024, 256, 0, stream>>>(keys, sw, pctx);
    context2_kernel<<<B_, 256, 0, stream>>>(pctx, ctx);
  } else {
    context_atomic_kernel<<<1024, 256, 0, stream>>>(keys, sw, ctx);
  }
}

// Round 5
// 629.910 us; speedup vs baseline: 1.3491x; 1.0553x over previous
//
#include <hip/hip_runtime.h>
#include <hip/hip_bf16.h>
#include <math.h>

// BahdanauAttention: B=32, S=2048, H=1024, fp32 in/out.
// R5: 5 dispatches (prep merged: keys->bf16, Ua->bf16, qproj); scores writes
// per-colblock partials (no atomics, no memset); ILP-boosted streaming kernels.
// Scores GEMM: m97 structure, 128x128 tile, GLDS width-16, 16x16x32 bf16 MFMA,
// fast-tanh epilogue. XCD swizzle keeps the 8 colblocks of a rowblock on one XCD.

#define B_ 32
#define S_ 2048
#define H_ 1024
#define M_ (B_ * S_)

#define CONV_BLOCKS 8192   // keys fp32->bf16
#define UA_BLOCKS 32       // Ua fp32->bf16
#define QP_BLOCKS 512      // qproj

typedef __bf16 bf16x8 __attribute__((ext_vector_type(8)));
typedef float floatx4 __attribute__((ext_vector_type(4)));

__device__ inline unsigned bf16_rne(float f) {
  unsigned u = __builtin_bit_cast(unsigned, f);
  return (u + 0x7fffu + ((u >> 16) & 1u)) >> 16;
}
__device__ inline unsigned pk2(float x, float y) {
  return bf16_rne(x) | (bf16_rne(y) << 16);
}

// tanh via v_exp_f32 + v_rcp_f32 (~7 ops); rel err ~1e-6, << bf16 GEMM noise.
__device__ inline float fast_tanh(float x) {
  const float xc = fminf(fmaxf(x, -8.f), 8.f);
  const float e = __expf(2.f * xc);
  return (e - 1.f) * __builtin_amdgcn_rcpf(e + 1.f);
}

#define GLDS(g, l)                                                    \
  __builtin_amdgcn_global_load_lds(                                   \
      (const __attribute__((address_space(1))) void*)(g),             \
      (__attribute__((address_space(3))) void*)(l), 16, 0, 0)

__device__ inline uint4 conv8(const float4* s2) {
  const float4 a = s2[0], b = s2[1];
  uint4 o;
  o.x = pk2(a.x, a.y); o.y = pk2(a.z, a.w);
  o.z = pk2(b.x, b.y); o.w = pk2(b.z, b.w);
  return o;
}

// ---------------- prep: keys->bf16 | Ua->bf16 | qproj, block-ranged ----------------
__global__ __launch_bounds__(256) void prep_kernel(
    const float* __restrict__ keys, const float* __restrict__ Ua_w,
    const float* __restrict__ query, const float* __restrict__ Wa_w,
    const float* __restrict__ Wa_b, const float* __restrict__ Ua_b,
    unsigned short* __restrict__ kbf, unsigned short* __restrict__ ubf,
    float* __restrict__ qp, int do_convert) {
  const int blk = blockIdx.x;
  const int tid = threadIdx.x;
  if (blk < CONV_BLOCKS) {
    if (!do_convert) return;
    // keys: 8.39M 16B-chunks; 4 independent chunks/thread (8 loads in flight).
    const int tg = blk * 256 + tid;  // [0, 2097152)
#pragma unroll
    for (int c = 0; c < 4; ++c) {
      const size_t idx = (size_t)c * 2097152 + tg;
      ((uint4*)kbf)[idx] = conv8((const float4*)keys + idx * 2);
    }
  } else if (blk < CONV_BLOCKS + UA_BLOCKS) {
    if (!do_convert) return;
    const int tg = (blk - CONV_BLOCKS) * 256 + tid;  // [0, 8192)
#pragma unroll
    for (int c = 0; c < 16; ++c) {
      const size_t idx = (size_t)c * 8192 + tg;  // < 131072
      ((uint4*)ubf)[idx] = conv8((const float4*)Ua_w + idx * 2);
    }
  } else {
    // qproj: block = (b, 64-o slice). Wa read 64 rows/block coalesced; query in LDS.
    const int bl = blk - CONV_BLOCKS - UA_BLOCKS;  // [0, 512)
    const int b = bl >> 4;
    const int os = (bl & 15) * 64;
    const int lane = tid & 63;
    const int w = tid >> 6;
    __shared__ float qsh[H_];
    *(float4*)&qsh[tid * 4] = *(const float4*)(query + (size_t)b * H_ + tid * 4);
    __syncthreads();
    for (int t = 0; t < 16; ++t) {
      const int o = os + w * 16 + t;
      const float* wr = Wa_w + (size_t)o * H_;
      float p = 0.f;
#pragma unroll
      for (int j = 0; j < 16; ++j) p += wr[lane + 64 * j] * qsh[lane + 64 * j];
#pragma unroll
      for (int m = 32; m; m >>= 1) p += __shfl_xor(p, m);
      if (lane == 0) qp[b * H_ + o] = p + Wa_b[o] + Ua_b[o];
    }
  }
}

// XCD swizzle: 8 colblocks of a rowblock share idx%8 -> same XCD L2 keys tile.
__device__ inline void swizzle_rc(int idx, int& rb, int& cb) {
  cb = (idx >> 3) & 7;
  rb = (idx & 7) | ((idx >> 6) << 3);
}
__device__ inline int chunk_f(int r) { return (r & 3) ^ ((r >> 2) & 3); }

// ---------------- scores: bf16 GEMM + tanh/Va epilogue -> 8 partial arrays ----------------
__global__ __launch_bounds__(256) void scores_bf16_kernel(
    const unsigned short* __restrict__ kbf, const unsigned short* __restrict__ ubf,
    const float* __restrict__ qp, const float* __restrict__ Va_w,
    float* __restrict__ sp) {  // sp[cb][M_]
  const int tid = threadIdx.x;
  int rb, cb;
  swizzle_rc(blockIdx.x, rb, cb);
  const int row0 = rb * 128, c0 = cb * 128;
  const int bq = row0 >> 11;
  const int lane = tid & 63;
  const int w = tid >> 6;
  const int wm = w >> 1, wn = w & 1;
  const int q4 = lane >> 4, n16 = lane & 15;

  __shared__ __align__(16) unsigned short Asm[128][32];
  __shared__ __align__(16) unsigned short Bsm[128][32];
  __shared__ float red[2][128];

  floatx4 acc[4][4];
#pragma unroll
  for (int i = 0; i < 4; ++i)
#pragma unroll
    for (int j = 0; j < 4; ++j) acc[i][j] = {0.f, 0.f, 0.f, 0.f};

  const int r0a = w * 32;
  const int lr = lane >> 2;
  const int lc = ((lane & 3) ^ chunk_f(lr)) * 8;
  const unsigned short* gA0 = kbf + (size_t)(row0 + r0a + lr) * H_ + lc;
  const unsigned short* gA1 = kbf + (size_t)(row0 + r0a + 16 + lr) * H_ + lc;
  const unsigned short* gB0 = ubf + (size_t)(c0 + r0a + lr) * H_ + lc;
  const unsigned short* gB1 = ubf + (size_t)(c0 + r0a + 16 + lr) * H_ + lc;
  unsigned short* lA0 = &Asm[r0a][0];
  unsigned short* lA1 = &Asm[r0a + 16][0];
  unsigned short* lB0 = &Bsm[r0a][0];
  unsigned short* lB1 = &Bsm[r0a + 16][0];

  const int fn = chunk_f(n16);

  for (int kt = 0; kt < 32; ++kt) {
    const int k0 = kt * 32;
    __syncthreads();
    GLDS(gA0 + k0, lA0);
    GLDS(gA1 + k0, lA1);
    GLDS(gB0 + k0, lB0);
    GLDS(gB1 + k0, lB1);
    __syncthreads();
    bf16x8 af[4], bfr[4];
#pragma unroll
    for (int i = 0; i < 4; ++i)
      af[i] = *(const bf16x8*)&Asm[wm * 64 + i * 16 + n16][(q4 ^ fn) * 8];
#pragma unroll
    for (int j = 0; j < 4; ++j)
      bfr[j] = *(const bf16x8*)&Bsm[wn * 64 + j * 16 + n16][(q4 ^ fn) * 8];
#pragma unroll
    for (int i = 0; i < 4; ++i)
#pragma unroll
      for (int j = 0; j < 4; ++j)
        acc[i][j] = __builtin_amdgcn_mfma_f32_16x16x32_bf16(af[i], bfr[j], acc[i][j], 0, 0, 0);
  }

  float rsum[4][4];
#pragma unroll
  for (int i = 0; i < 4; ++i)
#pragma unroll
    for (int r = 0; r < 4; ++r) rsum[i][r] = 0.f;
#pragma unroll
  for (int j = 0; j < 4; ++j) {
    const int col = c0 + wn * 64 + j * 16 + n16;
    const float qv = qp[bq * H_ + col];
    const float vv = Va_w[col];
#pragma unroll
    for (int i = 0; i < 4; ++i)
#pragma unroll
      for (int r = 0; r < 4; ++r)
        rsum[i][r] += fast_tanh(acc[i][j][r] + qv) * vv;
  }
#pragma unroll
  for (int i = 0; i < 4; ++i)
#pragma unroll
    for (int r = 0; r < 4; ++r) {
      float v = rsum[i][r];
      v += __shfl_xor(v, 1);
      v += __shfl_xor(v, 2);
      v += __shfl_xor(v, 4);
      v += __shfl_xor(v, 8);
      rsum[i][r] = v;
    }
  if (n16 == 0) {
#pragma unroll
    for (int i = 0; i < 4; ++i)
#pragma unroll
      for (int r = 0; r < 4; ++r)
        red[wn][wm * 64 + i * 16 + q4 * 4 + r] = rsum[i][r];
  }
  __syncthreads();
  if (tid < 128) sp[(size_t)cb * M_ + row0 + tid] = red[0][tid] + red[1][tid];
}

// ---------------- fallback scores (fp32 sources, in-kernel convert) ----------------
__global__ __launch_bounds__(256) void scores_f32_kernel(
    const float* __restrict__ keys, const float* __restrict__ Ua_w,
    const float* __restrict__ qp, const float* __restrict__ Va_w,
    float* __restrict__ sp) {
  const int tid = threadIdx.x;
  int rb, cb;
  swizzle_rc(blockIdx.x, rb, cb);
  const int row0 = rb * 128, c0 = cb * 128;
  const int bq = row0 >> 11;
  const int lane = tid & 63;
  const int w = tid >> 6;
  const int wm = w >> 1, wn = w & 1;
  const int q4 = lane >> 4, n16 = lane & 15;

  __shared__ __align__(16) unsigned short Asm[128][40];
  __shared__ __align__(16) unsigned short Bsm[128][40];
  __shared__ float red[2][128];

  floatx4 acc[4][4];
#pragma unroll
  for (int i = 0; i < 4; ++i)
#pragma unroll
    for (int j = 0; j < 4; ++j) acc[i][j] = {0.f, 0.f, 0.f, 0.f};

  for (int kt = 0; kt < 32; ++kt) {
    const int k0 = kt * 32;
    __syncthreads();
#pragma unroll
    for (int rep = 0; rep < 4; ++rep) {
      const int idx4 = rep * 256 + tid;
      const int r = idx4 >> 3;
      const int c4 = (idx4 & 7) << 2;
      const float4 va = *(const float4*)(keys + (size_t)(row0 + r) * H_ + k0 + c4);
      *(uint2*)&Asm[r][c4] = make_uint2(pk2(va.x, va.y), pk2(va.z, va.w));
      const float4 vb = *(const float4*)(Ua_w + (size_t)(c0 + r) * H_ + k0 + c4);
      *(uint2*)&Bsm[r][c4] = make_uint2(pk2(vb.x, vb.y), pk2(vb.z, vb.w));
    }
    __syncthreads();
    bf16x8 af[4], bfr[4];
#pragma unroll
    for (int i = 0; i < 4; ++i)
      af[i] = *(const bf16x8*)&Asm[wm * 64 + i * 16 + n16][q4 * 8];
#pragma unroll
    for (int j = 0; j < 4; ++j)
      bfr[j] = *(const bf16x8*)&Bsm[wn * 64 + j * 16 + n16][q4 * 8];
#pragma unroll
    for (int i = 0; i < 4; ++i)
#pragma unroll
      for (int j = 0; j < 4; ++j)
        acc[i][j] = __builtin_amdgcn_mfma_f32_16x16x32_bf16(af[i], bfr[j], acc[i][j], 0, 0, 0);
  }

  float rsum[4][4];
#pragma unroll
  for (int i = 0; i < 4; ++i)
#pragma unroll
    for (int r = 0; r < 4; ++r) rsum[i][r] = 0.f;
#pragma unroll
  for (int j = 0; j < 4; ++j) {
    const int col = c0 + wn * 64 + j * 16 + n16;
    const float qv = qp[bq * H_ + col];
    const float vv = Va_w[col];
#pragma unroll
    for (int i = 0; i < 4; ++i)
#pragma unroll
      for (int r = 0; r < 4; ++r)
        rsum[i][r] += fast_tanh(acc[i][j][r] + qv) * vv;
  }
#pragma unroll
  for (int i = 0; i < 4; ++i)
#pragma unroll
    for (int r = 0; r < 4; ++r) {
      float v = rsum[i][r];
      v += __shfl_xor(v, 1);
      v += __shfl_xor(v, 2);
      v += __shfl_xor(v, 4);
      v += __shfl_xor(v, 8);
      rsum[i][r] = v;
    }
  if (n16 == 0) {
#pragma unroll
    for (int i = 0; i < 4; ++i)
#pragma unroll
      for (int r = 0; r < 4; ++r)
        red[wn][wm * 64 + i * 16 + q4 * 4 + r] = rsum[i][r];
  }
  __syncthreads();
  if (tid < 128) sp[(size_t)cb * M_ + row0 + tid] = red[0][tid] + red[1][tid];
}

// ---------------- softmax: sum 8 partials, softmax over S, write weights ----------------
__global__ __launch_bounds__(256) void softmax_kernel(
    const float* __restrict__ sp, float* __restrict__ sw) {
  const int b = blockIdx.x, tid = threadIdx.x;
  float v[8];
#pragma unroll
  for (int k = 0; k < 8; ++k) {
    const size_t base = (size_t)b * S_ + tid + 256 * k;
    float s = 0.f;
#pragma unroll
    for (int j = 0; j < 8; ++j) s += sp[(size_t)j * M_ + base];
    v[k] = s;
  }
  float mx = v[0];
#pragma unroll
  for (int k = 1; k < 8; ++k) mx = fmaxf(mx, v[k]);
#pragma unroll
  for (int m = 32; m; m >>= 1) mx = fmaxf(mx, __shfl_xor(mx, m));
  __shared__ float sred[4], ssum[4];
  if ((tid & 63) == 0) sred[tid >> 6] = mx;
  __syncthreads();
  mx = fmaxf(fmaxf(sred[0], sred[1]), fmaxf(sred[2], sred[3]));
  float e[8], s = 0.f;
#pragma unroll
  for (int k = 0; k < 8; ++k) { e[k] = __expf(v[k] - mx); s += e[k]; }
#pragma unroll
  for (int m = 32; m; m >>= 1) s += __shfl_xor(s, m);
  if ((tid & 63) == 0) ssum[tid >> 6] = s;
  __syncthreads();
  s = ssum[0] + ssum[1] + ssum[2] + ssum[3];
  const float inv = 1.0f / s;
#pragma unroll
  for (int k = 0; k < 8; ++k) sw[b * S_ + tid + 256 * k] = e[k] * inv;
}

// ---------------- context stage 1: (b, 32-s chunk) partials, register-blocked ----------------
__global__ __launch_bounds__(256) void context1_kernel(
    const float* __restrict__ keys, const float* __restrict__ weights,
    float* __restrict__ pctx) {
  const int b = blockIdx.x >> 6;
  const int ch = blockIdx.x & 63;
  const int s0 = ch * 32;
  const int h4 = threadIdx.x;  // float4 index
  const float4* kp4 = (const float4*)(keys + (size_t)(b * S_ + s0) * H_) + h4;
  const float4* wp4 = (const float4*)(weights + b * S_ + s0);
  float4 acc = {0.f, 0.f, 0.f, 0.f};
#pragma unroll
  for (int sq = 0; sq < 8; ++sq) {
    const float4 wv = wp4[sq];
    const float4 k0 = kp4[(sq * 4 + 0) * 256];
    const float4 k1 = kp4[(sq * 4 + 1) * 256];
    const float4 k2 = kp4[(sq * 4 + 2) * 256];
    const float4 k3 = kp4[(sq * 4 + 3) * 256];
    acc.x += wv.x * k0.x + wv.y * k1.x + wv.z * k2.x + wv.w * k3.x;
    acc.y += wv.x * k0.y + wv.y * k1.y + wv.z * k2.y + wv.w * k3.y;
    acc.z += wv.x * k0.z + wv.y * k1.z + wv.z * k2.z + wv.w * k3.z;
    acc.w += wv.x * k0.w + wv.y * k1.w + wv.z * k2.w + wv.w * k3.w;
  }
  *(float4*)(pctx + ((size_t)(b * 64 + ch)) * H_ + h4 * 4) = acc;
}

// ---------------- context stage 2: reduce 64 partials ----------------
__global__ __launch_bounds__(256) void context2_kernel(
    const float* __restrict__ pctx, float* __restrict__ ctx) {
  const int b = blockIdx.x;
  const int h4 = threadIdx.x * 4;
  float4 acc = {0.f, 0.f, 0.f, 0.f};
#pragma unroll 8
  for (int c = 0; c < 64; ++c) {
    const float4 v = *(const float4*)(pctx + ((size_t)(b * 64 + c)) * H_ + h4);
    acc.x += v.x; acc.y += v.y; acc.z += v.z; acc.w += v.w;
  }
  *(float4*)(ctx + b * H_ + h4) = acc;
}

extern "C" void kernel_launch(void* const* d_in, const int* in_sizes, int n_in,
                              void* d_out, int out_size, void* d_ws, size_t ws_size,
                              hipStream_t stream) {
  const float* query = (const float*)d_in[0];
  const float* keys  = (const float*)d_in[1];
  const float* Wa_w  = (const float*)d_in[2];
  const float* Wa_b  = (const float*)d_in[3];
  const float* Ua_w  = (const float*)d_in[4];
  const float* Ua_b  = (const float*)d_in[5];
  const float* Va_w  = (const float*)d_in[6];
  // d_in[7] = Va_b (softmax shift-invariant), d_in[8] = idx — unused.

  float* out = (float*)d_out;
  float* ctx = out;
  float* sw  = out + B_ * H_;

  // ws layout: qp 128K | sp 2M | pctx 8M | kbf 128M | ubf 2M
  const size_t qpb = (size_t)B_ * H_ * 4;
  const size_t spb = (size_t)8 * M_ * 4;
  const size_t pcb = (size_t)B_ * 64 * H_ * 4;
  const size_t kb  = (size_t)M_ * H_ * 2;
  const size_t ub  = (size_t)H_ * H_ * 2;
  float* qp = (float*)d_ws;
  float* sp = (float*)((char*)d_ws + qpb);
  float* pctx = (float*)((char*)d_ws + qpb + spb);
  unsigned short* kbf = (unsigned short*)((char*)d_ws + qpb + spb + pcb);
  unsigned short* ubf = (unsigned short*)((char*)d_ws + qpb + spb + pcb + kb);
  const bool fast = ws_size >= qpb + spb + pcb + kb + ub;

  prep_kernel<<<CONV_BLOCKS + UA_BLOCKS + QP_BLOCKS, 256, 0, stream>>>(
      keys, Ua_w, query, Wa_w, Wa_b, Ua_b, kbf, ubf, qp, fast ? 1 : 0);
  if (fast) {
    scores_bf16_kernel<<<4096, 256, 0, stream>>>(kbf, ubf, qp, Va_w, sp);
  } else {
    scores_f32_kernel<<<4096, 256, 0, stream>>>(keys, Ua_w, qp, Va_w, sp);
  }
  softmax_kernel<<<B_, 256, 0, stream>>>(sp, sw);
  context1_kernel<<<2048, 256, 0, stream>>>(keys, sw, pctx);
  context2_kernel<<<B_, 256, 0, stream>>>(pctx, ctx);
}